// Round 1
// baseline (1478.989 us; speedup 1.0000x reference)
//
#include <hip/hip_runtime.h>
#include <math.h>

#define N_NODES 100000
#define N_EDGES 1600000
#define F_DIM 64

// ---------------- degree count (int atomics) ----------------
__global__ __launch_bounds__(256) void count_deg_k(const int* __restrict__ dst,
                                                   int* __restrict__ cnt, int E) {
    int i = blockIdx.x * 256 + threadIdx.x;
    if (i < E) atomicAdd(&cnt[dst[i]], 1);
}

// ---------------- inv sqrt of degree (deg = cnt + 1 self loop) ----------------
__global__ __launch_bounds__(256) void inv_sqrt_k(const int* __restrict__ cnt,
                                                  float* __restrict__ inv, int N) {
    int i = blockIdx.x * 256 + threadIdx.x;
    if (i < N) inv[i] = rsqrtf((float)(cnt[i] + 1));
}

// ---------------- linear h = x*W + b ; out = h * inv[n]^2 (self loop) ----------------
__global__ __launch_bounds__(256) void linear_k(const float* __restrict__ x,
                                                const float* __restrict__ W,
                                                const float* __restrict__ bias,
                                                const float* __restrict__ inv,
                                                float* __restrict__ h,
                                                float* __restrict__ out, int N) {
    __shared__ float Ws[F_DIM][F_DIM];
    __shared__ float bs[F_DIM];
    for (int i = threadIdx.x; i < F_DIM * F_DIM; i += 256) Ws[i >> 6][i & 63] = W[i];
    if (threadIdx.x < F_DIM) bs[threadIdx.x] = bias[threadIdx.x];
    __syncthreads();

    int n = blockIdx.x * 256 + threadIdx.x;
    if (n >= N) return;

    float xr[F_DIM];
    const float4* xp = (const float4*)(x + (size_t)n * F_DIM);
#pragma unroll
    for (int k4 = 0; k4 < 16; ++k4) {
        float4 v = xp[k4];
        xr[k4 * 4 + 0] = v.x; xr[k4 * 4 + 1] = v.y;
        xr[k4 * 4 + 2] = v.z; xr[k4 * 4 + 3] = v.w;
    }
    float invn = inv[n];
    float selfw = invn * invn;
    float4* hp = (float4*)(h + (size_t)n * F_DIM);
    float4* op = (float4*)(out + (size_t)n * F_DIM);

#pragma unroll 1
    for (int f0 = 0; f0 < F_DIM; f0 += 4) {
        float a0 = bs[f0 + 0], a1 = bs[f0 + 1], a2 = bs[f0 + 2], a3 = bs[f0 + 3];
#pragma unroll
        for (int k = 0; k < F_DIM; ++k) {
            float xv = xr[k];
            a0 += xv * Ws[k][f0 + 0];
            a1 += xv * Ws[k][f0 + 1];
            a2 += xv * Ws[k][f0 + 2];
            a3 += xv * Ws[k][f0 + 3];
        }
        float4 hv = {a0, a1, a2, a3};
        hp[f0 >> 2] = hv;
        float4 ov = {a0 * selfw, a1 * selfw, a2 * selfw, a3 * selfw};
        op[f0 >> 2] = ov;
    }
}

// ---------------- edge scatter: out[dst] += h[src] * inv[src]*inv[dst] ----------------
__global__ __launch_bounds__(256) void scatter_k(const int* __restrict__ src,
                                                 const int* __restrict__ dst,
                                                 const float* __restrict__ h,
                                                 const float* __restrict__ inv,
                                                 float* __restrict__ out, int E) {
    int tid = blockIdx.x * 256 + threadIdx.x;
    int e = tid >> 4;
    if (e >= E) return;
    int lane = tid & 15;
    int s = src[e];
    int d = dst[e];
    float norm = inv[s] * inv[d];
    float4 v = *(const float4*)(h + (size_t)s * F_DIM + lane * 4);
    float* o = out + (size_t)d * F_DIM + lane * 4;
    atomicAdd(o + 0, v.x * norm);
    atomicAdd(o + 1, v.y * norm);
    atomicAdd(o + 2, v.z * norm);
    atomicAdd(o + 3, v.w * norm);
}

// ---------------- gelu (tanh approximation, jax.nn.gelu default) ----------------
__device__ __forceinline__ float gelu1(float x) {
    float x3 = x * x * x;
    float t = tanhf(0.7978845608028654f * (x + 0.044715f * x3));
    return 0.5f * x * (1.0f + t);
}

__global__ __launch_bounds__(256) void gelu_k(float* __restrict__ out, int n4) {
    int i = blockIdx.x * 256 + threadIdx.x;
    if (i < n4) {
        float4 v = ((float4*)out)[i];
        v.x = gelu1(v.x); v.y = gelu1(v.y); v.z = gelu1(v.z); v.w = gelu1(v.w);
        ((float4*)out)[i] = v;
    }
}

extern "C" void kernel_launch(void* const* d_in, const int* in_sizes, int n_in,
                              void* d_out, int out_size, void* d_ws, size_t ws_size,
                              hipStream_t stream) {
    const float* x    = (const float*)d_in[0];
    const int*   ei   = (const int*)d_in[1];
    const float* W    = (const float*)d_in[2];
    const float* bias = (const float*)d_in[3];
    float* out = (float*)d_out;

    // workspace layout
    float* h   = (float*)d_ws;                       // N*64 floats = 25.6 MB
    float* inv = h + (size_t)N_NODES * F_DIM;        // N floats
    int*   cnt = (int*)(inv + N_NODES);              // N ints

    const int* src = ei;             // edge_index[0]
    const int* dst = ei + N_EDGES;   // edge_index[1]

    hipMemsetAsync(cnt, 0, N_NODES * sizeof(int), stream);

    count_deg_k<<<(N_EDGES + 255) / 256, 256, 0, stream>>>(dst, cnt, N_EDGES);
    inv_sqrt_k<<<(N_NODES + 255) / 256, 256, 0, stream>>>(cnt, inv, N_NODES);
    linear_k<<<(N_NODES + 255) / 256, 256, 0, stream>>>(x, W, bias, inv, h, out, N_NODES);

    // 16 threads per edge, float4 per thread
    long long scatter_threads = (long long)N_EDGES * 16;
    scatter_k<<<(int)((scatter_threads + 255) / 256), 256, 0, stream>>>(src, dst, h, inv, out, N_EDGES);

    gelu_k<<<(N_NODES * F_DIM / 4 + 255) / 256, 256, 0, stream>>>(out, N_NODES * F_DIM / 4);
}

// Round 2
// 323.780 us; speedup vs baseline: 4.5679x; 4.5679x over previous
//
#include <hip/hip_runtime.h>
#include <math.h>

#define N_NODES 100000
#define N_EDGES 1600000
#define F_DIM 64
#define SCAN_TILE 1024   // 256 threads x 4 items

// ---------------- degree count (int atomics) ----------------
__global__ __launch_bounds__(256) void count_deg_k(const int* __restrict__ dst,
                                                   int* __restrict__ cnt, int E) {
    int i = blockIdx.x * 256 + threadIdx.x;
    if (i < E) atomicAdd(&cnt[dst[i]], 1);
}

// ---------------- inv sqrt of degree (deg = cnt + 1 self loop) ----------------
__global__ __launch_bounds__(256) void inv_sqrt_k(const int* __restrict__ cnt,
                                                  float* __restrict__ inv, int N) {
    int i = blockIdx.x * 256 + threadIdx.x;
    if (i < N) inv[i] = rsqrtf((float)(cnt[i] + 1));
}

// ---------------- scan stage 1: per-block exclusive scan + block sums ----------------
__global__ __launch_bounds__(256) void scan1_k(const int* __restrict__ cnt,
                                               int* __restrict__ part,
                                               int* __restrict__ bsum, int N) {
    __shared__ int ls[256];
    int base = blockIdx.x * SCAN_TILE;
    int vals[4];
    int tsum = 0;
#pragma unroll
    for (int j = 0; j < 4; ++j) {
        int idx = base + threadIdx.x * 4 + j;
        vals[j] = (idx < N) ? cnt[idx] : 0;
        tsum += vals[j];
    }
    ls[threadIdx.x] = tsum;
    __syncthreads();
    for (int off = 1; off < 256; off <<= 1) {
        int v = (threadIdx.x >= off) ? ls[threadIdx.x - off] : 0;
        __syncthreads();
        ls[threadIdx.x] += v;
        __syncthreads();
    }
    int excl = ls[threadIdx.x] - tsum;
#pragma unroll
    for (int j = 0; j < 4; ++j) {
        int idx = base + threadIdx.x * 4 + j;
        if (idx < N) part[idx] = excl;
        excl += vals[j];
    }
    if (threadIdx.x == 255) bsum[blockIdx.x] = ls[255];
}

// ---------------- scan stage 2: exclusive scan of block sums (single block) ----------------
__global__ __launch_bounds__(128) void scan2_k(int* __restrict__ bsum, int NB) {
    __shared__ int ls[128];
    int v = (threadIdx.x < NB) ? bsum[threadIdx.x] : 0;
    ls[threadIdx.x] = v;
    __syncthreads();
    for (int off = 1; off < 128; off <<= 1) {
        int p = (threadIdx.x >= off) ? ls[threadIdx.x - off] : 0;
        __syncthreads();
        ls[threadIdx.x] += p;
        __syncthreads();
    }
    if (threadIdx.x < NB) bsum[threadIdx.x] = ls[threadIdx.x] - v;
}

// ---------------- scan stage 3: finalize rowptr; init cursor (in-place in part) ----------------
__global__ __launch_bounds__(256) void scan3_k(int* __restrict__ part,
                                               const int* __restrict__ bsum,
                                               int* __restrict__ rowptr, int N, int E) {
    int i = blockIdx.x * 256 + threadIdx.x;
    if (i < N) {
        int v = part[i] + bsum[i >> 10];
        rowptr[i] = v;
        part[i] = v;   // part becomes the fill cursor
    }
    if (i == 0) rowptr[N] = E;
}

// ---------------- bucket fill: CSR column list grouped by dst ----------------
__global__ __launch_bounds__(256) void fill_k(const int* __restrict__ src,
                                              const int* __restrict__ dst,
                                              int* __restrict__ cursor,
                                              int* __restrict__ esrc, int E) {
    int e = blockIdx.x * 256 + threadIdx.x;
    if (e >= E) return;
    int d = dst[e];
    int pos = atomicAdd(&cursor[d], 1);
    esrc[pos] = src[e];
}

// ---------------- linear h = x*W + b ----------------
__global__ __launch_bounds__(256) void linear_k(const float* __restrict__ x,
                                                const float* __restrict__ W,
                                                const float* __restrict__ bias,
                                                float* __restrict__ h, int N) {
    __shared__ float Ws[F_DIM][F_DIM];
    __shared__ float bs[F_DIM];
    for (int i = threadIdx.x; i < F_DIM * F_DIM; i += 256) Ws[i >> 6][i & 63] = W[i];
    if (threadIdx.x < F_DIM) bs[threadIdx.x] = bias[threadIdx.x];
    __syncthreads();

    int n = blockIdx.x * 256 + threadIdx.x;
    if (n >= N) return;

    float xr[F_DIM];
    const float4* xp = (const float4*)(x + (size_t)n * F_DIM);
#pragma unroll
    for (int k4 = 0; k4 < 16; ++k4) {
        float4 v = xp[k4];
        xr[k4 * 4 + 0] = v.x; xr[k4 * 4 + 1] = v.y;
        xr[k4 * 4 + 2] = v.z; xr[k4 * 4 + 3] = v.w;
    }
    float4* hp = (float4*)(h + (size_t)n * F_DIM);
#pragma unroll 1
    for (int f0 = 0; f0 < F_DIM; f0 += 4) {
        float a0 = bs[f0 + 0], a1 = bs[f0 + 1], a2 = bs[f0 + 2], a3 = bs[f0 + 3];
#pragma unroll
        for (int k = 0; k < F_DIM; ++k) {
            float xv = xr[k];
            a0 += xv * Ws[k][f0 + 0];
            a1 += xv * Ws[k][f0 + 1];
            a2 += xv * Ws[k][f0 + 2];
            a3 += xv * Ws[k][f0 + 3];
        }
        float4 hv = {a0, a1, a2, a3};
        hp[f0 >> 2] = hv;
    }
}

// ---------------- gelu (tanh approximation, jax.nn.gelu default) ----------------
__device__ __forceinline__ float gelu1(float x) {
    float x3 = x * x * x;
    float t = tanhf(0.7978845608028654f * (x + 0.044715f * x3));
    return 0.5f * x * (1.0f + t);
}

// ---------------- gather: one wave per node, lane = feature ----------------
__global__ __launch_bounds__(256) void gather_k(const float* __restrict__ h,
                                                const float* __restrict__ inv,
                                                const int* __restrict__ rowptr,
                                                const int* __restrict__ esrc,
                                                float* __restrict__ out, int N) {
    int n = blockIdx.x * 4 + (threadIdx.x >> 6);
    if (n >= N) return;
    int lane = threadIdx.x & 63;

    int beg = rowptr[n];
    int end = rowptr[n + 1];
    float invn = inv[n];
    // self loop: contributes h[n]*invn^2; factor one invn at the end
    float acc = h[(size_t)n * F_DIM + lane] * invn;

    int e = beg;
    for (; e + 1 < end; e += 2) {
        int s0 = esrc[e];
        int s1 = esrc[e + 1];
        float w0 = inv[s0];
        float w1 = inv[s1];
        float v0 = h[(size_t)s0 * F_DIM + lane];
        float v1 = h[(size_t)s1 * F_DIM + lane];
        acc += v0 * w0 + v1 * w1;
    }
    if (e < end) {
        int s0 = esrc[e];
        acc += h[(size_t)s0 * F_DIM + lane] * inv[s0];
    }
    acc *= invn;
    out[(size_t)n * F_DIM + lane] = gelu1(acc);
}

extern "C" void kernel_launch(void* const* d_in, const int* in_sizes, int n_in,
                              void* d_out, int out_size, void* d_ws, size_t ws_size,
                              hipStream_t stream) {
    const float* x    = (const float*)d_in[0];
    const int*   ei   = (const int*)d_in[1];
    const float* W    = (const float*)d_in[2];
    const float* bias = (const float*)d_in[3];
    float* out = (float*)d_out;

    // workspace layout (~33.6 MB)
    float* h      = (float*)d_ws;                     // N*64 floats
    float* inv    = h + (size_t)N_NODES * F_DIM;      // N floats
    int*   cnt    = (int*)(inv + N_NODES);            // N ints
    int*   part   = cnt + N_NODES;                    // N ints (scan partial, then cursor)
    int*   rowptr = part + N_NODES;                   // N+1 ints
    int*   bsum   = rowptr + (N_NODES + 1);           // 128 ints
    int*   esrc   = bsum + 128;                       // E ints

    const int* src = ei;             // edge_index[0]
    const int* dst = ei + N_EDGES;   // edge_index[1]

    const int NB = (N_NODES + SCAN_TILE - 1) / SCAN_TILE;  // 98

    hipMemsetAsync(cnt, 0, N_NODES * sizeof(int), stream);

    count_deg_k<<<(N_EDGES + 255) / 256, 256, 0, stream>>>(dst, cnt, N_EDGES);
    inv_sqrt_k<<<(N_NODES + 255) / 256, 256, 0, stream>>>(cnt, inv, N_NODES);
    scan1_k<<<NB, 256, 0, stream>>>(cnt, part, bsum, N_NODES);
    scan2_k<<<1, 128, 0, stream>>>(bsum, NB);
    scan3_k<<<(N_NODES + 255) / 256, 256, 0, stream>>>(part, bsum, rowptr, N_NODES, N_EDGES);
    linear_k<<<(N_NODES + 255) / 256, 256, 0, stream>>>(x, W, bias, h, N_NODES);
    fill_k<<<(N_EDGES + 255) / 256, 256, 0, stream>>>(src, dst, part, esrc, N_EDGES);
    gather_k<<<(N_NODES + 3) / 4, 256, 0, stream>>>(h, inv, rowptr, esrc, out, N_NODES);
}

// Round 3
// 213.021 us; speedup vs baseline: 6.9429x; 1.5199x over previous
//
#include <hip/hip_runtime.h>
#include <math.h>

#define N_NODES 100000
#define N_EDGES 1600000
#define F_DIM 64
#define NBUCK 196          // ceil(100000 / 512)
#define PASSA_EPT 16       // edges per thread in passA
#define PASSA_TILE (256 * PASSA_EPT)   // 4096

// ---------------- bucket count: edges per dst>>9 bucket ----------------
__global__ __launch_bounds__(256) void bcount_k(const int* __restrict__ dst,
                                                int* __restrict__ bktcnt, int E) {
    __shared__ int lc[NBUCK];
    for (int i = threadIdx.x; i < NBUCK; i += 256) lc[i] = 0;
    __syncthreads();
    int base = blockIdx.x * 2048;
#pragma unroll
    for (int j = 0; j < 8; ++j) {
        int idx = base + j * 256 + threadIdx.x;
        if (idx < E) atomicAdd(&lc[dst[idx] >> 9], 1);
    }
    __syncthreads();
    for (int i = threadIdx.x; i < NBUCK; i += 256)
        if (lc[i]) atomicAdd(&bktcnt[i], lc[i]);
}

// ---------------- bucket scan (single block): bases + cursors ----------------
__global__ __launch_bounds__(256) void bscan_k(const int* __restrict__ bktcnt,
                                               int* __restrict__ bbase,
                                               int* __restrict__ bcur,
                                               int* __restrict__ rowptr, int E) {
    __shared__ int ls[256];
    int v = (threadIdx.x < NBUCK) ? bktcnt[threadIdx.x] : 0;
    ls[threadIdx.x] = v;
    __syncthreads();
    for (int off = 1; off < 256; off <<= 1) {
        int p = (threadIdx.x >= off) ? ls[threadIdx.x - off] : 0;
        __syncthreads();
        ls[threadIdx.x] += p;
        __syncthreads();
    }
    if (threadIdx.x < NBUCK) {
        int excl = ls[threadIdx.x] - v;
        bbase[threadIdx.x] = excl;
        bcur[threadIdx.x] = excl;
    }
    if (threadIdx.x == 0) {
        bbase[NBUCK] = E;
        rowptr[N_NODES] = E;
    }
}

// ---------------- passA: bucket the edges (packed src | ldst<<17) ----------------
__global__ __launch_bounds__(256) void passA_k(const int* __restrict__ src,
                                               const int* __restrict__ dst,
                                               int* __restrict__ bcur,
                                               unsigned int* __restrict__ tmp, int E) {
    __shared__ int lcnt[NBUCK];
    __shared__ int lbase[NBUCK];
    for (int i = threadIdx.x; i < NBUCK; i += 256) lcnt[i] = 0;
    __syncthreads();

    int sreg[PASSA_EPT], dreg[PASSA_EPT];
    int base = blockIdx.x * PASSA_TILE;
#pragma unroll
    for (int j = 0; j < PASSA_EPT; ++j) {
        int idx = base + j * 256 + threadIdx.x;
        if (idx < E) {
            sreg[j] = src[idx];
            dreg[j] = dst[idx];
            atomicAdd(&lcnt[dreg[j] >> 9], 1);
        } else {
            dreg[j] = -1;
        }
    }
    __syncthreads();
    for (int b = threadIdx.x; b < NBUCK; b += 256) {
        int c = lcnt[b];
        lbase[b] = c ? atomicAdd(&bcur[b], c) : 0;
    }
    __syncthreads();
    for (int b = threadIdx.x; b < NBUCK; b += 256) lcnt[b] = 0;
    __syncthreads();
#pragma unroll
    for (int j = 0; j < PASSA_EPT; ++j) {
        if (dreg[j] >= 0) {
            int b = dreg[j] >> 9;
            int r = atomicAdd(&lcnt[b], 1);
            tmp[lbase[b] + r] = (unsigned int)sreg[j] | ((unsigned int)(dreg[j] & 511) << 17);
        }
    }
}

// ---------------- passB: per-bucket node counts, scan, rowptr/inv, final scatter ----------------
__global__ __launch_bounds__(256) void passB_k(const unsigned int* __restrict__ tmp,
                                               const int* __restrict__ bbase,
                                               int* __restrict__ rowptr,
                                               float* __restrict__ inv,
                                               int* __restrict__ esrc) {
    __shared__ int cnt[512];
    __shared__ int cur[512];
    __shared__ int ls[256];
    int b = blockIdx.x;
    int node0 = b << 9;
    int beg = bbase[b];
    int end = bbase[b + 1];

    cnt[threadIdx.x] = 0;
    cnt[threadIdx.x + 256] = 0;
    __syncthreads();
    for (int i = beg + threadIdx.x; i < end; i += 256)
        atomicAdd(&cnt[tmp[i] >> 17], 1);
    __syncthreads();

    int a0 = cnt[2 * threadIdx.x];
    int a1 = cnt[2 * threadIdx.x + 1];
    int tsum = a0 + a1;
    ls[threadIdx.x] = tsum;
    __syncthreads();
    for (int off = 1; off < 256; off <<= 1) {
        int p = (threadIdx.x >= off) ? ls[threadIdx.x - off] : 0;
        __syncthreads();
        ls[threadIdx.x] += p;
        __syncthreads();
    }
    int excl = ls[threadIdx.x] - tsum;
    int p0 = beg + excl;
    int p1 = p0 + a0;
    cur[2 * threadIdx.x] = p0;
    cur[2 * threadIdx.x + 1] = p1;
    int n0 = node0 + 2 * threadIdx.x;
    if (n0 < N_NODES) {
        rowptr[n0] = p0;
        inv[n0] = rsqrtf((float)(a0 + 1));
    }
    if (n0 + 1 < N_NODES) {
        rowptr[n0 + 1] = p1;
        inv[n0 + 1] = rsqrtf((float)(a1 + 1));
    }
    __syncthreads();

    for (int i = beg + threadIdx.x; i < end; i += 256) {
        unsigned int p = tmp[i];
        int ld = p >> 17;
        int pos = atomicAdd(&cur[ld], 1);
        esrc[pos] = (int)(p & 0x1FFFF);
    }
}

// ---------------- linear h = x*W + b ----------------
__global__ __launch_bounds__(256) void linear_k(const float* __restrict__ x,
                                                const float* __restrict__ W,
                                                const float* __restrict__ bias,
                                                float* __restrict__ h, int N) {
    __shared__ float Ws[F_DIM][F_DIM];
    __shared__ float bs[F_DIM];
    for (int i = threadIdx.x; i < F_DIM * F_DIM; i += 256) Ws[i >> 6][i & 63] = W[i];
    if (threadIdx.x < F_DIM) bs[threadIdx.x] = bias[threadIdx.x];
    __syncthreads();

    int n = blockIdx.x * 256 + threadIdx.x;
    if (n >= N) return;

    float xr[F_DIM];
    const float4* xp = (const float4*)(x + (size_t)n * F_DIM);
#pragma unroll
    for (int k4 = 0; k4 < 16; ++k4) {
        float4 v = xp[k4];
        xr[k4 * 4 + 0] = v.x; xr[k4 * 4 + 1] = v.y;
        xr[k4 * 4 + 2] = v.z; xr[k4 * 4 + 3] = v.w;
    }
    float4* hp = (float4*)(h + (size_t)n * F_DIM);
#pragma unroll 1
    for (int f0 = 0; f0 < F_DIM; f0 += 4) {
        float a0 = bs[f0 + 0], a1 = bs[f0 + 1], a2 = bs[f0 + 2], a3 = bs[f0 + 3];
#pragma unroll
        for (int k = 0; k < F_DIM; ++k) {
            float xv = xr[k];
            a0 += xv * Ws[k][f0 + 0];
            a1 += xv * Ws[k][f0 + 1];
            a2 += xv * Ws[k][f0 + 2];
            a3 += xv * Ws[k][f0 + 3];
        }
        float4 hv = {a0, a1, a2, a3};
        hp[f0 >> 2] = hv;
    }
}

// ---------------- gelu (tanh approximation, jax.nn.gelu default) ----------------
__device__ __forceinline__ float gelu1(float x) {
    float x3 = x * x * x;
    float t = tanhf(0.7978845608028654f * (x + 0.044715f * x3));
    return 0.5f * x * (1.0f + t);
}

// ---------------- gather: one wave per node, lane = feature ----------------
__global__ __launch_bounds__(256) void gather_k(const float* __restrict__ h,
                                                const float* __restrict__ inv,
                                                const int* __restrict__ rowptr,
                                                const int* __restrict__ esrc,
                                                float* __restrict__ out, int N) {
    int n = blockIdx.x * 4 + (threadIdx.x >> 6);
    if (n >= N) return;
    int lane = threadIdx.x & 63;

    int beg = rowptr[n];
    int end = rowptr[n + 1];
    float invn = inv[n];
    float acc = h[(size_t)n * F_DIM + lane] * invn;   // self loop (×invn again below)

    int e = beg;
    for (; e + 1 < end; e += 2) {
        int s0 = esrc[e];
        int s1 = esrc[e + 1];
        float w0 = inv[s0];
        float w1 = inv[s1];
        float v0 = h[(size_t)s0 * F_DIM + lane];
        float v1 = h[(size_t)s1 * F_DIM + lane];
        acc += v0 * w0 + v1 * w1;
    }
    if (e < end) {
        int s0 = esrc[e];
        acc += h[(size_t)s0 * F_DIM + lane] * inv[s0];
    }
    acc *= invn;
    out[(size_t)n * F_DIM + lane] = gelu1(acc);
}

extern "C" void kernel_launch(void* const* d_in, const int* in_sizes, int n_in,
                              void* d_out, int out_size, void* d_ws, size_t ws_size,
                              hipStream_t stream) {
    const float* x    = (const float*)d_in[0];
    const int*   ei   = (const int*)d_in[1];
    const float* W    = (const float*)d_in[2];
    const float* bias = (const float*)d_in[3];
    float* out = (float*)d_out;

    const int* src = ei;             // edge_index[0]
    const int* dst = ei + N_EDGES;   // edge_index[1]

    // workspace layout (~32.8 MB); tmp aliases the head of h (linear runs after passB)
    int*   esrc   = (int*)d_ws;                        // E ints
    int*   rowptr = esrc + N_EDGES;                    // N+1 ints
    float* inv    = (float*)(rowptr + N_NODES + 1);    // N floats
    int*   bbase  = (int*)(inv + N_NODES);             // NBUCK+1 ints
    int*   bcur   = bbase + NBUCK + 1;                 // NBUCK ints
    int*   bktcnt = bcur + NBUCK;                      // NBUCK ints
    size_t off    = (size_t)(bktcnt + NBUCK) - (size_t)d_ws;
    off = (off + 15) & ~(size_t)15;
    float* h      = (float*)((char*)d_ws + off);       // N*64 floats
    unsigned int* tmp = (unsigned int*)h;              // E uints (aliased, dead before linear)

    hipMemsetAsync(bktcnt, 0, NBUCK * sizeof(int), stream);

    bcount_k<<<(N_EDGES + 2047) / 2048, 256, 0, stream>>>(dst, bktcnt, N_EDGES);
    bscan_k<<<1, 256, 0, stream>>>(bktcnt, bbase, bcur, rowptr, N_EDGES);
    passA_k<<<(N_EDGES + PASSA_TILE - 1) / PASSA_TILE, 256, 0, stream>>>(src, dst, bcur, tmp, N_EDGES);
    passB_k<<<NBUCK, 256, 0, stream>>>(tmp, bbase, rowptr, inv, esrc);
    linear_k<<<(N_NODES + 255) / 256, 256, 0, stream>>>(x, W, bias, h, N_NODES);
    gather_k<<<(N_NODES + 3) / 4, 256, 0, stream>>>(h, inv, rowptr, esrc, out, N_NODES);
}

// Round 4
// 177.259 us; speedup vs baseline: 8.3437x; 1.2018x over previous
//
#include <hip/hip_runtime.h>
#include <hip/hip_fp16.h>
#include <math.h>

#define N_NODES 100000
#define N_EDGES 1600000
#define F_DIM 64
#define NBUCK 196          // ceil(100000 / 512)
#define PASSA_EPT 16       // edges per thread in passA
#define PASSA_TILE (256 * PASSA_EPT)   // 4096

// ---------------- bucket count: edges per dst>>9 bucket ----------------
__global__ __launch_bounds__(256) void bcount_k(const int* __restrict__ dst,
                                                int* __restrict__ bktcnt, int E) {
    __shared__ int lc[NBUCK];
    for (int i = threadIdx.x; i < NBUCK; i += 256) lc[i] = 0;
    __syncthreads();
    int base = blockIdx.x * 2048;
#pragma unroll
    for (int j = 0; j < 8; ++j) {
        int idx = base + j * 256 + threadIdx.x;
        if (idx < E) atomicAdd(&lc[dst[idx] >> 9], 1);
    }
    __syncthreads();
    for (int i = threadIdx.x; i < NBUCK; i += 256)
        if (lc[i]) atomicAdd(&bktcnt[i], lc[i]);
}

// ---------------- bucket scan (single block): bases + cursors ----------------
__global__ __launch_bounds__(256) void bscan_k(const int* __restrict__ bktcnt,
                                               int* __restrict__ bbase,
                                               int* __restrict__ bcur,
                                               int* __restrict__ rowptr, int E) {
    __shared__ int ls[256];
    int v = (threadIdx.x < NBUCK) ? bktcnt[threadIdx.x] : 0;
    ls[threadIdx.x] = v;
    __syncthreads();
    for (int off = 1; off < 256; off <<= 1) {
        int p = (threadIdx.x >= off) ? ls[threadIdx.x - off] : 0;
        __syncthreads();
        ls[threadIdx.x] += p;
        __syncthreads();
    }
    if (threadIdx.x < NBUCK) {
        int excl = ls[threadIdx.x] - v;
        bbase[threadIdx.x] = excl;
        bcur[threadIdx.x] = excl;
    }
    if (threadIdx.x == 0) {
        bbase[NBUCK] = E;
        rowptr[N_NODES] = E;
    }
}

// ---------------- passA: bucket the edges (packed src | ldst<<17) ----------------
__global__ __launch_bounds__(256) void passA_k(const int* __restrict__ src,
                                               const int* __restrict__ dst,
                                               int* __restrict__ bcur,
                                               unsigned int* __restrict__ tmp, int E) {
    __shared__ int lcnt[NBUCK];
    __shared__ int lbase[NBUCK];
    for (int i = threadIdx.x; i < NBUCK; i += 256) lcnt[i] = 0;
    __syncthreads();

    int sreg[PASSA_EPT], dreg[PASSA_EPT];
    int base = blockIdx.x * PASSA_TILE;
#pragma unroll
    for (int j = 0; j < PASSA_EPT; ++j) {
        int idx = base + j * 256 + threadIdx.x;
        if (idx < E) {
            sreg[j] = src[idx];
            dreg[j] = dst[idx];
            atomicAdd(&lcnt[dreg[j] >> 9], 1);
        } else {
            dreg[j] = -1;
        }
    }
    __syncthreads();
    for (int b = threadIdx.x; b < NBUCK; b += 256) {
        int c = lcnt[b];
        lbase[b] = c ? atomicAdd(&bcur[b], c) : 0;
    }
    __syncthreads();
    for (int b = threadIdx.x; b < NBUCK; b += 256) lcnt[b] = 0;
    __syncthreads();
#pragma unroll
    for (int j = 0; j < PASSA_EPT; ++j) {
        if (dreg[j] >= 0) {
            int b = dreg[j] >> 9;
            int r = atomicAdd(&lcnt[b], 1);
            tmp[lbase[b] + r] = (unsigned int)sreg[j] | ((unsigned int)(dreg[j] & 511) << 17);
        }
    }
}

// ---------------- passB: per-bucket node counts, scan, rowptr/inv, final scatter ----------------
__global__ __launch_bounds__(256) void passB_k(const unsigned int* __restrict__ tmp,
                                               const int* __restrict__ bbase,
                                               int* __restrict__ rowptr,
                                               float* __restrict__ inv,
                                               int* __restrict__ esrc) {
    __shared__ int cnt[512];
    __shared__ int cur[512];
    __shared__ int ls[256];
    int b = blockIdx.x;
    int node0 = b << 9;
    int beg = bbase[b];
    int end = bbase[b + 1];

    cnt[threadIdx.x] = 0;
    cnt[threadIdx.x + 256] = 0;
    __syncthreads();
    for (int i = beg + threadIdx.x; i < end; i += 256)
        atomicAdd(&cnt[tmp[i] >> 17], 1);
    __syncthreads();

    int a0 = cnt[2 * threadIdx.x];
    int a1 = cnt[2 * threadIdx.x + 1];
    int tsum = a0 + a1;
    ls[threadIdx.x] = tsum;
    __syncthreads();
    for (int off = 1; off < 256; off <<= 1) {
        int p = (threadIdx.x >= off) ? ls[threadIdx.x - off] : 0;
        __syncthreads();
        ls[threadIdx.x] += p;
        __syncthreads();
    }
    int excl = ls[threadIdx.x] - tsum;
    int p0 = beg + excl;
    int p1 = p0 + a0;
    cur[2 * threadIdx.x] = p0;
    cur[2 * threadIdx.x + 1] = p1;
    int n0 = node0 + 2 * threadIdx.x;
    if (n0 < N_NODES) {
        rowptr[n0] = p0;
        inv[n0] = rsqrtf((float)(a0 + 1));
    }
    if (n0 + 1 < N_NODES) {
        rowptr[n0 + 1] = p1;
        inv[n0 + 1] = rsqrtf((float)(a1 + 1));
    }
    __syncthreads();

    for (int i = beg + threadIdx.x; i < end; i += 256) {
        unsigned int p = tmp[i];
        int ld = p >> 17;
        int pos = atomicAdd(&cur[ld], 1);
        esrc[pos] = (int)(p & 0x1FFFF);
    }
}

// ---------------- linear h = x*W + b (fp16 output) ----------------
__global__ __launch_bounds__(256) void linear_k(const float* __restrict__ x,
                                                const float* __restrict__ W,
                                                const float* __restrict__ bias,
                                                __half* __restrict__ h, int N) {
    __shared__ float Ws[F_DIM][F_DIM];
    __shared__ float bs[F_DIM];
    for (int i = threadIdx.x; i < F_DIM * F_DIM; i += 256) Ws[i >> 6][i & 63] = W[i];
    if (threadIdx.x < F_DIM) bs[threadIdx.x] = bias[threadIdx.x];
    __syncthreads();

    int n = blockIdx.x * 256 + threadIdx.x;
    if (n >= N) return;

    float xr[F_DIM];
    const float4* xp = (const float4*)(x + (size_t)n * F_DIM);
#pragma unroll
    for (int k4 = 0; k4 < 16; ++k4) {
        float4 v = xp[k4];
        xr[k4 * 4 + 0] = v.x; xr[k4 * 4 + 1] = v.y;
        xr[k4 * 4 + 2] = v.z; xr[k4 * 4 + 3] = v.w;
    }
    __half* hp = h + (size_t)n * F_DIM;
#pragma unroll 1
    for (int f0 = 0; f0 < F_DIM; f0 += 4) {
        float a0 = bs[f0 + 0], a1 = bs[f0 + 1], a2 = bs[f0 + 2], a3 = bs[f0 + 3];
#pragma unroll
        for (int k = 0; k < F_DIM; ++k) {
            float xv = xr[k];
            a0 += xv * Ws[k][f0 + 0];
            a1 += xv * Ws[k][f0 + 1];
            a2 += xv * Ws[k][f0 + 2];
            a3 += xv * Ws[k][f0 + 3];
        }
        union { __half2 h2[2]; float2 f2; } u;
        u.h2[0] = __floats2half2_rn(a0, a1);
        u.h2[1] = __floats2half2_rn(a2, a3);
        *((float2*)(hp + f0)) = u.f2;
    }
}

// ---------------- gelu (tanh approximation, jax.nn.gelu default) ----------------
__device__ __forceinline__ float gelu1(float x) {
    float x3 = x * x * x;
    float t = tanhf(0.7978845608028654f * (x + 0.044715f * x3));
    return 0.5f * x * (1.0f + t);
}

// ---------------- gather: one wave per node; half-wave per edge; half2 per lane ----------------
__global__ __launch_bounds__(256) void gather_k(const __half* __restrict__ h,
                                                const float* __restrict__ inv,
                                                const int* __restrict__ rowptr,
                                                const int* __restrict__ esrc,
                                                float* __restrict__ out, int N) {
    int n = blockIdx.x * 4 + (threadIdx.x >> 6);
    if (n >= N) return;
    int lane = threadIdx.x & 63;
    int half_id = lane >> 5;    // 0: even edges, 1: odd edges
    int fl = lane & 31;         // feature-pair index (features 2*fl, 2*fl+1)

    int beg = rowptr[n];
    int cntE = rowptr[n + 1] - beg;
    float invn = inv[n];

    float ax = 0.f, ay = 0.f;
    int k = half_id;
    // unroll 2: four edges in flight per wave
    for (; k + 2 < cntE; k += 4) {
        int s0 = esrc[beg + k];
        int s1 = esrc[beg + k + 2];
        float w0 = inv[s0];
        float w1 = inv[s1];
        __half2 v0 = *((const __half2*)(h + (size_t)s0 * F_DIM) + fl);
        __half2 v1 = *((const __half2*)(h + (size_t)s1 * F_DIM) + fl);
        float2 f0 = __half22float2(v0);
        float2 f1 = __half22float2(v1);
        ax += f0.x * w0 + f1.x * w1;
        ay += f0.y * w0 + f1.y * w1;
    }
    for (; k < cntE; k += 2) {
        int s0 = esrc[beg + k];
        float w0 = inv[s0];
        __half2 v0 = *((const __half2*)(h + (size_t)s0 * F_DIM) + fl);
        float2 f0 = __half22float2(v0);
        ax += f0.x * w0;
        ay += f0.y * w0;
    }
    // merge even/odd halves (lane i <-> lane i+32 hold same feature pair)
    ax += __shfl_xor(ax, 32);
    ay += __shfl_xor(ay, 32);
    // self loop once, after merge
    __half2 sv = *((const __half2*)(h + (size_t)n * F_DIM) + fl);
    float2 sf = __half22float2(sv);
    ax = (ax + sf.x * invn) * invn;
    ay = (ay + sf.y * invn) * invn;

    if (half_id == 0) {
        float2 o;
        o.x = gelu1(ax);
        o.y = gelu1(ay);
        ((float2*)(out + (size_t)n * F_DIM))[fl] = o;
    }
}

extern "C" void kernel_launch(void* const* d_in, const int* in_sizes, int n_in,
                              void* d_out, int out_size, void* d_ws, size_t ws_size,
                              hipStream_t stream) {
    const float* x    = (const float*)d_in[0];
    const int*   ei   = (const int*)d_in[1];
    const float* W    = (const float*)d_in[2];
    const float* bias = (const float*)d_in[3];
    float* out = (float*)d_out;

    const int* src = ei;             // edge_index[0]
    const int* dst = ei + N_EDGES;   // edge_index[1]

    // workspace layout (~20 MB); tmp aliases the head of h (linear runs after passB)
    int*   esrc   = (int*)d_ws;                        // E ints
    int*   rowptr = esrc + N_EDGES;                    // N+1 ints
    float* inv    = (float*)(rowptr + N_NODES + 1);    // N floats
    int*   bbase  = (int*)(inv + N_NODES);             // NBUCK+1 ints
    int*   bcur   = bbase + NBUCK + 1;                 // NBUCK ints
    int*   bktcnt = bcur + NBUCK;                      // NBUCK ints
    size_t off    = (size_t)(bktcnt + NBUCK) - (size_t)d_ws;
    off = (off + 15) & ~(size_t)15;
    __half* h     = (__half*)((char*)d_ws + off);      // N*64 halves = 12.8 MB
    unsigned int* tmp = (unsigned int*)h;              // E uints (aliased, dead before linear)

    hipMemsetAsync(bktcnt, 0, NBUCK * sizeof(int), stream);

    bcount_k<<<(N_EDGES + 2047) / 2048, 256, 0, stream>>>(dst, bktcnt, N_EDGES);
    bscan_k<<<1, 256, 0, stream>>>(bktcnt, bbase, bcur, rowptr, N_EDGES);
    passA_k<<<(N_EDGES + PASSA_TILE - 1) / PASSA_TILE, 256, 0, stream>>>(src, dst, bcur, tmp, N_EDGES);
    passB_k<<<NBUCK, 256, 0, stream>>>(tmp, bbase, rowptr, inv, esrc);
    linear_k<<<(N_NODES + 255) / 256, 256, 0, stream>>>(x, W, bias, h, N_NODES);
    gather_k<<<(N_NODES + 3) / 4, 256, 0, stream>>>(h, inv, rowptr, esrc, out, N_NODES);
}